// Round 1
// baseline (51.470 us; speedup 1.0000x reference)
//
#include <hip/hip_runtime.h>
#include <math.h>

#define OUT_C   384
#define IN_C    384
#define KG      16
#define NUM_IN  16
#define NUM_OUT 16
#define ICH     192   // ic rows handled per block (half of IN_C)
#define PAD     17    // LDS row stride in floats (odd -> conflict-free gather)

__global__ __launch_bounds__(256) void gsub_kernel(
    const float* __restrict__ in_H,
    const float* __restrict__ out_H,
    const float* __restrict__ weight,
    float* __restrict__ out)
{
    __shared__ float s_frac[NUM_IN * NUM_OUT];
    __shared__ int   s_i0[NUM_IN * NUM_OUT];
    __shared__ float s_w[ICH * PAD];

    const int t = threadIdx.x;
    const int oc = blockIdx.x >> 1;
    const int h  = blockIdx.x & 1;
    const int ic_base = h * ICH;

    // --- precompute frac / i0 for all 256 (ni,no) pairs (one per thread) ---
    {
        const int ni = t >> 4;
        const int no = t & 15;
        const float TWOPI = 6.283185307179586f;
        float c = in_H[ni] - out_H[no];          // in_H + (-out_H)
        float r = fmodf(c, TWOPI);
        if (r < 0.0f) r += TWOPI;                // jnp.mod semantics (non-negative)
        float pos = r * ((float)KG / TWOPI);     // coords / spacing
        float b = floorf(pos);
        s_i0[t]   = ((int)b) & (KG - 1);
        s_frac[t] = pos - b;
    }

    // --- stage 192 weight rows (192 x 16 f32 = 12 KB) into padded LDS ---
    // global source is contiguous: coalesced float4 loads, 3 per thread
    const float4* wsrc = (const float4*)(weight + ((size_t)oc * IN_C + ic_base) * KG);
    #pragma unroll
    for (int j = 0; j < 3; ++j) {
        int f = t + j * 256;                     // float4 index 0..767
        float4 v = wsrc[f];
        int ic_l = f >> 2;
        int kq   = (f & 3) * 4;
        float* dst = &s_w[ic_l * PAD + kq];
        dst[0] = v.x; dst[1] = v.y; dst[2] = v.z; dst[3] = v.w;
    }
    __syncthreads();

    // --- main loop: 16 ni x 192 ic = 3072 (ni,ic) pairs / 256 threads = 12 iters
    // waves stay ni-uniform (192 = 3*64), so i0 is wave-uniform per read.
    for (int iter = 0; iter < 12; ++iter) {
        int p    = iter * 256 + t;               // 0..3071
        int ni   = p / ICH;
        int ic_l = p - ni * ICH;

        const float* wrow = &s_w[ic_l * PAD];
        const float* fr   = &s_frac[ni * 16];
        const int*   iz   = &s_i0[ni * 16];

        float4 res[4];
        #pragma unroll
        for (int q = 0; q < 4; ++q) {
            float r[4];
            #pragma unroll
            for (int j2 = 0; j2 < 4; ++j2) {
                int no = q * 4 + j2;
                int i0 = iz[no];
                int i1 = (i0 + 1) & (KG - 1);
                float f = fr[no];
                // match reference: (1-frac)*sig[i0] + frac*sig[i1]
                r[j2] = (1.0f - f) * wrow[i0] + f * wrow[i1];
            }
            res[q] = make_float4(r[0], r[1], r[2], r[3]);
        }

        // out[oc][ni][ic][no] : 16 contiguous f32 per thread, 64B aligned
        float4* op = (float4*)(out +
            ((((size_t)oc * NUM_IN + ni) * IN_C) + ic_base + ic_l) * NUM_OUT);
        op[0] = res[0]; op[1] = res[1]; op[2] = res[2]; op[3] = res[3];
    }
}

extern "C" void kernel_launch(void* const* d_in, const int* in_sizes, int n_in,
                              void* d_out, int out_size, void* d_ws, size_t ws_size,
                              hipStream_t stream) {
    const float* in_H   = (const float*)d_in[0];
    const float* out_H  = (const float*)d_in[1];
    const float* weight = (const float*)d_in[2];
    float* o = (float*)d_out;
    gsub_kernel<<<OUT_C * 2, 256, 0, stream>>>(in_H, out_H, weight, o);
}

// Round 2
// 29.801 us; speedup vs baseline: 1.7271x; 1.7271x over previous
//
#include <hip/hip_runtime.h>
#include <math.h>

#define OUT_C   384
#define IN_C    384
#define KG      16
#define NUM_IN  16
#define NUM_OUT 16
#define ICH     192   // ic rows per block (half of IN_C)
#define PAD     17    // LDS row stride: 16 taps + circular dup w[16]=w[0]

__global__ __launch_bounds__(256) void gsub_kernel(
    const float* __restrict__ in_H,
    const float* __restrict__ out_H,
    const float* __restrict__ weight,
    float* __restrict__ out)
{
    __shared__ float s_frac[NUM_IN * NUM_OUT];
    __shared__ int   s_i0[NUM_IN * NUM_OUT];
    __shared__ float s_w[ICH * PAD];

    const int t = threadIdx.x;
    const int oc = blockIdx.x >> 1;
    const int h  = blockIdx.x & 1;
    const int ic_base = h * ICH;

    // --- per-(ni,no) interpolation params (one pair per thread) ---
    {
        const int ni = t >> 4;
        const int no = t & 15;
        const float TWOPI = 6.283185307179586f;
        float c = in_H[ni] - out_H[no];          // in_H + (-out_H)
        float r = fmodf(c, TWOPI);
        if (r < 0.0f) r += TWOPI;                // jnp.mod semantics
        float pos = r * ((float)KG / TWOPI);
        float b = floorf(pos);
        s_i0[t]   = ((int)b) & (KG - 1);
        s_frac[t] = pos - b;
    }

    // --- stage 192 weight rows into padded LDS; dup tap 0 at slot 16 ---
    const float4* wsrc = (const float4*)(weight + ((size_t)oc * IN_C + ic_base) * KG);
    #pragma unroll
    for (int j = 0; j < 3; ++j) {
        int f = t + j * 256;                     // float4 index 0..767
        float4 v = wsrc[f];
        int ic_l = f >> 2;
        int kq   = (f & 3) * 4;
        float* dst = &s_w[ic_l * PAD + kq];
        dst[0] = v.x; dst[1] = v.y; dst[2] = v.z; dst[3] = v.w;
        if ((f & 3) == 0) s_w[ic_l * PAD + 16] = v.x;   // circular wrap dup
    }
    __syncthreads();

    // --- main loop: thread owns (q = no-quad, lic); wave stores are 1 KB contiguous
    const int q   = t & 3;                       // no-quad 0..3
    const int lic = t >> 2;                      // 0..63

    // out as float4: index = ((oc*16+ni)*384 + ic_base + ic)*4 + q
    float4* op = (float4*)out + (size_t)oc * 24576 + (size_t)(ic_base + lic) * 4 + q;
    const int fb = 4 * q;

    for (int ni = 0; ni < 16; ++ni) {
        const float* fr = &s_frac[ni * 16 + fb];
        const int*   iz = &s_i0[ni * 16 + fb];
        float f0 = fr[0], f1 = fr[1], f2 = fr[2], f3 = fr[3];
        int   a0 = iz[0], a1 = iz[1], a2 = iz[2], a3 = iz[3];

        #pragma unroll
        for (int r = 0; r < 3; ++r) {
            const float* wrow = &s_w[(r * 64 + lic) * PAD];
            // adjacent pairs (dup at slot 16 avoids mod) -> ds_read2_b32
            float x0 = wrow[a0], y0 = wrow[a0 + 1];
            float x1 = wrow[a1], y1 = wrow[a1 + 1];
            float x2 = wrow[a2], y2 = wrow[a2 + 1];
            float x3 = wrow[a3], y3 = wrow[a3 + 1];
            float4 v;
            v.x = fmaf(f0, y0 - x0, x0);
            v.y = fmaf(f1, y1 - x1, x1);
            v.z = fmaf(f2, y2 - x2, x2);
            v.w = fmaf(f3, y3 - x3, x3);
            op[ni * 1536 + r * 256] = v;
        }
    }
}

extern "C" void kernel_launch(void* const* d_in, const int* in_sizes, int n_in,
                              void* d_out, int out_size, void* d_ws, size_t ws_size,
                              hipStream_t stream) {
    const float* in_H   = (const float*)d_in[0];
    const float* out_H  = (const float*)d_in[1];
    const float* weight = (const float*)d_in[2];
    float* o = (float*)d_out;
    gsub_kernel<<<OUT_C * 2, 256, 0, stream>>>(in_H, out_H, weight, o);
}